// Round 2
// baseline (54.142 us; speedup 1.0000x reference)
//
#include <hip/hip_runtime.h>

#define OUTN 400
#define THRESH 0.7f
#define BB 32
#define HH 512
#define WW 512
#define CC 3
#define CHUNKS 16

// bounds layout per batch: [minR, maxR, minC, maxC]
__global__ void init_bounds_kernel(int* __restrict__ bounds) {
    int i = threadIdx.x;
    if (i < BB * 4) {
        int which = i & 3;
        bounds[i] = (which == 0 || which == 2) ? 0x7FFFFFFF : -1;
    }
}

__global__ void bounds_kernel(const float* __restrict__ tensor,
                              int* __restrict__ bounds) {
    const int blk   = blockIdx.x;
    const int b     = blk / CHUNKS;
    const int chunk = blk % CHUNKS;
    const int rows_per_chunk = HH / CHUNKS;          // 32
    const int f4_per_row     = WW / 4;               // 128
    const int n4             = rows_per_chunk * f4_per_row; // 4096

    const float4* base = (const float4*)(tensor + (size_t)b * HH * WW
                                                + (size_t)chunk * rows_per_chunk * WW);

    int minR = 0x7FFFFFFF, maxR = -1, minC = 0x7FFFFFFF, maxC = -1;

    for (int p = threadIdx.x; p < n4; p += blockDim.x) {
        float4 v = base[p];
        int row  = p / f4_per_row;            // chunk-relative
        int col0 = (p % f4_per_row) * 4;
        bool m0 = v.x > THRESH, m1 = v.y > THRESH, m2 = v.z > THRESH, m3 = v.w > THRESH;
        if (m0 | m1 | m2 | m3) {
            minR = min(minR, row);
            maxR = max(maxR, row);
            if (m0) { minC = min(minC, col0    ); maxC = max(maxC, col0    ); }
            if (m1) { minC = min(minC, col0 + 1); maxC = max(maxC, col0 + 1); }
            if (m2) { minC = min(minC, col0 + 2); maxC = max(maxC, col0 + 2); }
            if (m3) { minC = min(minC, col0 + 3); maxC = max(maxC, col0 + 3); }
        }
    }

    // 64-lane wave reduction
    #pragma unroll
    for (int off = 32; off > 0; off >>= 1) {
        minR = min(minR, __shfl_down(minR, off));
        maxR = max(maxR, __shfl_down(maxR, off));
        minC = min(minC, __shfl_down(minC, off));
        maxC = max(maxC, __shfl_down(maxC, off));
    }

    __shared__ int s[4];
    if (threadIdx.x == 0) { s[0] = 0x7FFFFFFF; s[1] = -1; s[2] = 0x7FFFFFFF; s[3] = -1; }
    __syncthreads();
    if ((threadIdx.x & 63) == 0) {
        atomicMin(&s[0], minR); atomicMax(&s[1], maxR);
        atomicMin(&s[2], minC); atomicMax(&s[3], maxC);
    }
    __syncthreads();
    if (threadIdx.x == 0 && s[1] >= 0) {
        int rbase = chunk * rows_per_chunk;
        atomicMin(&bounds[b * 4 + 0], s[0] + rbase);
        atomicMax(&bounds[b * 4 + 1], s[1] + rbase);
        atomicMin(&bounds[b * 4 + 2], s[2]);
        atomicMax(&bounds[b * 4 + 3], s[3]);
    }
}

__global__ void resize_kernel(const float* __restrict__ img,
                              const int* __restrict__ bounds,
                              float* __restrict__ out) {
    int idx = blockIdx.x * blockDim.x + threadIdx.x;
    if (idx >= BB * OUTN * OUTN) return;

    int ocol = idx % OUTN;
    int tmp  = idx / OUTN;
    int orow = tmp % OUTN;
    int b    = tmp / OUTN;

    int minR = bounds[b * 4 + 0];
    int maxR = bounds[b * 4 + 1];
    int minC = bounds[b * 4 + 2];
    int maxC = bounds[b * 4 + 3];
    // all-false mask => argmax semantics give [0, n-1]
    if (maxR < 0) { minR = 0; maxR = HH - 1; }
    if (maxC < 0) { minC = 0; maxC = WW - 1; }

    // rows (matches _axis_coords exactly)
    float sizeR = (float)(maxR - minR);
    float srcR  = ((float)orow + 0.5f) * sizeR / (float)OUTN - 0.5f;
    srcR = fminf(fmaxf(srcR, 0.0f), fmaxf(sizeR - 1.0f, 0.0f));
    int   i0 = (int)floorf(srcR);
    int   i1 = min(i0 + 1, max(maxR - minR - 1, 0));
    float wr = srcR - (float)i0;
    int r0 = minR + i0, r1 = minR + i1;

    // cols
    float sizeC = (float)(maxC - minC);
    float srcC  = ((float)ocol + 0.5f) * sizeC / (float)OUTN - 0.5f;
    srcC = fminf(fmaxf(srcC, 0.0f), fmaxf(sizeC - 1.0f, 0.0f));
    int   j0 = (int)floorf(srcC);
    int   j1 = min(j0 + 1, max(maxC - minC - 1, 0));
    float wc = srcC - (float)j0;
    int c0 = minC + j0, c1 = minC + j1;

    const float* ib  = img + (size_t)b * HH * WW * CC;
    const float* p00 = ib + ((size_t)r0 * WW + c0) * CC;
    const float* p01 = ib + ((size_t)r0 * WW + c1) * CC;
    const float* p10 = ib + ((size_t)r1 * WW + c0) * CC;
    const float* p11 = ib + ((size_t)r1 * WW + c1) * CC;

    float* o = out + (size_t)idx * CC;
    #pragma unroll
    for (int ch = 0; ch < CC; ++ch) {
        float a00 = p00[ch], a01 = p01[ch], a10 = p10[ch], a11 = p11[ch];
        float top = a00 * (1.0f - wc) + a01 * wc;
        float bot = a10 * (1.0f - wc) + a11 * wc;
        o[ch] = top * (1.0f - wr) + bot * wr;
    }
}

extern "C" void kernel_launch(void* const* d_in, const int* in_sizes, int n_in,
                              void* d_out, int out_size, void* d_ws, size_t ws_size,
                              hipStream_t stream) {
    const float* image  = (const float*)d_in[0];
    const float* tensor = (const float*)d_in[1];
    float* out = (float*)d_out;
    int*   bounds = (int*)d_ws;

    hipLaunchKernelGGL(init_bounds_kernel, dim3(1), dim3(128), 0, stream, bounds);
    hipLaunchKernelGGL(bounds_kernel, dim3(BB * CHUNKS), dim3(256), 0, stream,
                       tensor, bounds);

    int total  = BB * OUTN * OUTN;
    int blocks = (total + 255) / 256;
    hipLaunchKernelGGL(resize_kernel, dim3(blocks), dim3(256), 0, stream,
                       image, bounds, out);
}